// Round 1
// baseline (1034.844 us; speedup 1.0000x reference)
//
#include <hip/hip_runtime.h>
#include <hip/hip_bf16.h>

#define B_ 16
#define S_ 4096
#define DM_ 1280
#define DC_ 768
#define NC_ 384
#define SCALE_ 0.07905694150420949f

typedef __attribute__((ext_vector_type(8))) short bf16x8;
typedef __attribute__((ext_vector_type(4))) float f32x4;

__device__ __forceinline__ unsigned short f2bf(float f) {
    unsigned int u = __builtin_bit_cast(unsigned int, f);
    u = (u + 0x7FFFu + ((u >> 16) & 1u)) >> 16;
    return (unsigned short)u;
}

// ---------- transpose w_q (1280x1280) ----------
__global__ void k_transpose(const float* __restrict__ w, float* __restrict__ wt) {
    __shared__ float tile[32][33];
    int bx = blockIdx.x * 32, by = blockIdx.y * 32;
    int tx = threadIdx.x, ty = threadIdx.y;
    for (int i = ty; i < 32; i += 8)
        tile[i][tx] = w[(size_t)(by + i) * DM_ + bx + tx];
    __syncthreads();
    for (int i = ty; i < 32; i += 8)
        wt[(size_t)(bx + i) * DM_ + by + tx] = tile[tx][i];
}

// ---------- K/V projections: kv[j][b][k][e], j=0..5 ----------
// j: 0=K_anat(w_k) 1=V_anat(w_v) 2=K_dis(w_k_dis) 3=V_dis(w_v_dis) 4=K_delta(w_k_dis) 5=V_delta(w_v_dis)
__global__ void k_proj(const float* __restrict__ enc,
                       const float* __restrict__ wk, const float* __restrict__ wv,
                       const float* __restrict__ wkd, const float* __restrict__ wvd,
                       float* __restrict__ kv) {
    __shared__ float tok[16 * DC_];
    int bid = blockIdx.x;
    int j = bid / 80, rem = bid % 80, b = rem / 5, cb = rem % 5;
    int tid = threadIdx.x;
    int tok0 = (j < 2) ? 16 : ((j < 4) ? 0 : 32);   // anat=enc[16:32], dis=enc[0:16], delta=enc[32:48]
    const float* w = (j == 0) ? wk : (j == 1) ? wv : (j == 2 || j == 4) ? wkd : wvd;
    const float4* src = (const float4*)(enc + ((size_t)b * 48 + tok0) * DC_);
    float4* dst4 = (float4*)tok;
    for (int i = tid; i < 16 * DC_ / 4; i += 256) dst4[i] = src[i];
    __syncthreads();
    int e = cb * 256 + tid;
    float acc[16];
    #pragma unroll
    for (int k = 0; k < 16; k++) acc[k] = 0.f;
    for (int d0 = 0; d0 < DC_; d0 += 4) {
        float w0 = w[(size_t)(d0 + 0) * DM_ + e];
        float w1 = w[(size_t)(d0 + 1) * DM_ + e];
        float w2 = w[(size_t)(d0 + 2) * DM_ + e];
        float w3 = w[(size_t)(d0 + 3) * DM_ + e];
        #pragma unroll
        for (int k = 0; k < 16; k++) {
            float4 t4 = *(const float4*)&tok[k * DC_ + d0];
            acc[k] += t4.x * w0 + t4.y * w1 + t4.z * w2 + t4.w * w3;
        }
    }
    float* dst = kv + (((size_t)j * B_ + b) * 16) * DM_ + e;
    #pragma unroll
    for (int k = 0; k < 16; k++) dst[(size_t)k * DM_] = acc[k];
}

// ---------- A[b][c][d] bf16 (c=(x*8+h)*16+k), from wqT and K ----------
__global__ void k_abuild(const float* __restrict__ kv, const float* __restrict__ wqT,
                         unsigned short* __restrict__ At) {
    __shared__ float Ksl[16 * 160];
    int bid = blockIdx.x;
    int b = bid / 24, rem = bid % 24, x = rem / 8, h = rem % 8;
    int tid = threadIdx.x;
    const float* src = kv + (((size_t)(2 * x) * B_ + b) * 16) * DM_ + h * 160;
    for (int i = tid; i < 16 * 160; i += 256) {
        int k = i / 160, jj = i - k * 160;
        Ksl[i] = src[(size_t)k * DM_ + jj];
    }
    __syncthreads();
    for (int i = 0; i < 5; i++) {
        int d = i * 256 + tid;
        float acc[16];
        #pragma unroll
        for (int k = 0; k < 16; k++) acc[k] = 0.f;
        for (int jj = 0; jj < 160; jj += 4) {
            float w0 = wqT[(size_t)(h * 160 + jj + 0) * DM_ + d];
            float w1 = wqT[(size_t)(h * 160 + jj + 1) * DM_ + d];
            float w2 = wqT[(size_t)(h * 160 + jj + 2) * DM_ + d];
            float w3 = wqT[(size_t)(h * 160 + jj + 3) * DM_ + d];
            #pragma unroll
            for (int k = 0; k < 16; k++) {
                float4 t4 = *(const float4*)&Ksl[k * 160 + jj];
                acc[k] += t4.x * w0 + t4.y * w1 + t4.z * w2 + t4.w * w3;
            }
        }
        unsigned short* dst = At + ((size_t)b * NC_ + x * 128 + h * 16) * DM_ + d;
        #pragma unroll
        for (int k = 0; k < 16; k++) dst[(size_t)k * DM_] = f2bf(acc[k]);
    }
}

// ---------- U[b][e][c] bf16 (gates folded), from w_out and V ----------
__global__ void k_ubuild(const float* __restrict__ kv, const float* __restrict__ wout,
                         unsigned short* __restrict__ Ut) {
    __shared__ float Vsl[16 * 160];
    int bid = blockIdx.x;
    int b = bid / 24, rem = bid % 24, x = rem / 8, h = rem % 8;
    float gate = (x == 2) ? 1.0f : 0.5f;
    int tid = threadIdx.x;
    const float* src = kv + (((size_t)(2 * x + 1) * B_ + b) * 16) * DM_ + h * 160;
    for (int i = tid; i < 16 * 160; i += 256) {
        int k = i / 160, jj = i - k * 160;
        Vsl[i] = src[(size_t)k * DM_ + jj];
    }
    __syncthreads();
    for (int i = 0; i < 5; i++) {
        int e = i * 256 + tid;
        float acc[16];
        #pragma unroll
        for (int k = 0; k < 16; k++) acc[k] = 0.f;
        for (int jj = 0; jj < 160; jj += 4) {
            float w0 = wout[(size_t)(h * 160 + jj + 0) * DM_ + e];
            float w1 = wout[(size_t)(h * 160 + jj + 1) * DM_ + e];
            float w2 = wout[(size_t)(h * 160 + jj + 2) * DM_ + e];
            float w3 = wout[(size_t)(h * 160 + jj + 3) * DM_ + e];
            #pragma unroll
            for (int k = 0; k < 16; k++) {
                float4 t4 = *(const float4*)&Vsl[k * 160 + jj];
                acc[k] += t4.x * w0 + t4.y * w1 + t4.z * w2 + t4.w * w3;
            }
        }
        union { unsigned short s[16]; uint4 u[2]; } pk;
        #pragma unroll
        for (int k = 0; k < 16; k++) pk.s[k] = f2bf(acc[k] * gate);
        uint4* dst = (uint4*)(Ut + ((size_t)b * DM_ + e) * NC_ + x * 128 + h * 16);
        dst[0] = pk.u[0]; dst[1] = pk.u[1];
    }
}

// ---------- scores = hidden @ A^T, softmax per 16-group, P bf16 ----------
__global__ __launch_bounds__(256, 2)
void k_scores(const float* __restrict__ hid, const unsigned short* __restrict__ At,
              unsigned short* __restrict__ P) {
    __shared__ unsigned short pnl[NC_ * 40];   // 384 rows x 32 halfs, padded to 40
    int bid = blockIdx.x;
    int b = bid & 15, t = bid >> 4;            // bid%16=batch -> same-batch blocks share XCD L2
    int s0 = t * 64;
    int tid = threadIdx.x;
    int w = tid >> 6, l = tid & 63;
    int l15 = l & 15, l4 = l >> 4;
    f32x4 zero = {0.f, 0.f, 0.f, 0.f};
    f32x4 acc[24];
    #pragma unroll
    for (int g = 0; g < 24; g++) acc[g] = zero;
    const unsigned short* Ab = At + (size_t)b * NC_ * DM_;
    const float* hrow = hid + ((size_t)b * S_ + s0 + w * 16 + l15) * DM_;
    for (int kk = 0; kk < 40; kk++) {
        #pragma unroll
        for (int i = 0; i < 6; i++) {          // stage 384x32-half A panel
            int idx = tid + 256 * i;
            int c = idx >> 2, p = idx & 3;
            uint4 v = *(const uint4*)(Ab + (size_t)c * DM_ + kk * 32 + p * 8);
            *(uint4*)&pnl[c * 40 + p * 8] = v;
        }
        __syncthreads();
        const float4* hp = (const float4*)(hrow + kk * 32 + l4 * 8);
        float4 x0 = hp[0], x1 = hp[1];
        bf16x8 af;
        af[0] = (short)f2bf(x0.x); af[1] = (short)f2bf(x0.y);
        af[2] = (short)f2bf(x0.z); af[3] = (short)f2bf(x0.w);
        af[4] = (short)f2bf(x1.x); af[5] = (short)f2bf(x1.y);
        af[6] = (short)f2bf(x1.z); af[7] = (short)f2bf(x1.w);
        #pragma unroll
        for (int g = 0; g < 24; g++) {
            bf16x8 bf = *(const bf16x8*)&pnl[(g * 16 + l15) * 40 + l4 * 8];
            acc[g] = __builtin_amdgcn_mfma_f32_16x16x32_bf16(af, bf, acc[g], 0, 0, 0);
        }
        __syncthreads();
    }
    unsigned short* Pb = P + ((size_t)b * S_ + s0 + w * 16) * NC_;
    #pragma unroll
    for (int g = 0; g < 24; g++) {
        #pragma unroll
        for (int r = 0; r < 4; r++) {
            float v = acc[g][r] * SCALE_;
            float mx = v;
            mx = fmaxf(mx, __shfl_xor(mx, 1));
            mx = fmaxf(mx, __shfl_xor(mx, 2));
            mx = fmaxf(mx, __shfl_xor(mx, 4));
            mx = fmaxf(mx, __shfl_xor(mx, 8));
            float ex = __expf(v - mx);
            float sm = ex;
            sm += __shfl_xor(sm, 1);
            sm += __shfl_xor(sm, 2);
            sm += __shfl_xor(sm, 4);
            sm += __shfl_xor(sm, 8);
            float p = ex / sm;
            Pb[(size_t)(l4 * 4 + r) * NC_ + g * 16 + l15] = f2bf(p);
        }
    }
}

// ---------- out = P @ U + b_out + residual ----------
__global__ __launch_bounds__(256, 2)
void k_out(const unsigned short* __restrict__ P, const unsigned short* __restrict__ Ut,
           const float* __restrict__ hid, const float* __restrict__ bo,
           float* __restrict__ out) {
    __shared__ unsigned short pnl[256 * 40];   // 256 e-rows x 32 halfs, padded
    int bid = blockIdx.x;
    int b = bid & 15, t = bid >> 4;
    int s0 = t * 64;
    int tid = threadIdx.x;
    int w = tid >> 6, l = tid & 63;
    int l15 = l & 15, l4 = l >> 4;
    f32x4 zero = {0.f, 0.f, 0.f, 0.f};
    const unsigned short* Ub = Ut + (size_t)b * DM_ * NC_;
    const unsigned short* Prow = P + ((size_t)b * S_ + s0 + w * 16 + l15) * NC_;
    for (int ec = 0; ec < 5; ec++) {
        f32x4 acc[16];
        #pragma unroll
        for (int g = 0; g < 16; g++) acc[g] = zero;
        for (int kk = 0; kk < 12; kk++) {
            #pragma unroll
            for (int i = 0; i < 4; i++) {
                int idx = tid + 256 * i;
                int el = idx >> 2, p = idx & 3;
                uint4 v = *(const uint4*)(Ub + (size_t)(ec * 256 + el) * NC_ + kk * 32 + p * 8);
                *(uint4*)&pnl[el * 40 + p * 8] = v;
            }
            __syncthreads();
            bf16x8 pa = *(const bf16x8*)(Prow + kk * 32 + l4 * 8);
            #pragma unroll
            for (int g = 0; g < 16; g++) {
                bf16x8 bv = *(const bf16x8*)&pnl[(g * 16 + l15) * 40 + l4 * 8];
                acc[g] = __builtin_amdgcn_mfma_f32_16x16x32_bf16(pa, bv, acc[g], 0, 0, 0);
            }
            __syncthreads();
        }
        #pragma unroll
        for (int g = 0; g < 16; g++) {
            #pragma unroll
            for (int r = 0; r < 4; r++) {
                int srow = s0 + w * 16 + l4 * 4 + r;
                int e = ec * 256 + g * 16 + l15;
                size_t off = ((size_t)b * S_ + srow) * DM_ + e;
                out[off] = acc[g][r] + bo[e] + hid[off];
            }
        }
    }
}

extern "C" void kernel_launch(void* const* d_in, const int* in_sizes, int n_in,
                              void* d_out, int out_size, void* d_ws, size_t ws_size,
                              hipStream_t stream) {
    const float* hid  = (const float*)d_in[0];
    const float* enc  = (const float*)d_in[1];
    const float* wq   = (const float*)d_in[2];
    const float* wk   = (const float*)d_in[3];
    const float* wv   = (const float*)d_in[4];
    const float* wkd  = (const float*)d_in[5];
    const float* wvd  = (const float*)d_in[6];
    const float* wout = (const float*)d_in[7];
    const float* bo   = (const float*)d_in[8];
    float* out = (float*)d_out;

    char* ws = (char*)d_ws;
    float* kv            = (float*)(ws);                      //  7,864,320 B
    float* wqT           = (float*)(ws + 7864320);            //  6,553,600 B
    unsigned short* At   = (unsigned short*)(ws + 14417920);  // 15,728,640 B
    unsigned short* Ut   = (unsigned short*)(ws + 30146560);  // 15,728,640 B
    unsigned short* Pbuf = (unsigned short*)(ws + 45875200);  // 50,331,648 B  (total ~96.2 MB)

    k_transpose<<<dim3(40, 40), dim3(32, 8), 0, stream>>>(wq, wqT);
    k_proj<<<480, 256, 0, stream>>>(enc, wk, wv, wkd, wvd, kv);
    k_abuild<<<384, 256, 0, stream>>>(kv, wqT, At);
    k_ubuild<<<384, 256, 0, stream>>>(kv, wout, Ut);
    k_scores<<<1024, 256, 0, stream>>>(hid, At, Pbuf);
    k_out<<<1024, 256, 0, stream>>>(Pbuf, Ut, hid, bo, out);
}

// Round 2
// 629.211 us; speedup vs baseline: 1.6447x; 1.6447x over previous
//
#include <hip/hip_runtime.h>
#include <hip/hip_bf16.h>

#define B_ 16
#define S_ 4096
#define DM_ 1280
#define DC_ 768
#define NC_ 384
#define SCALE_ 0.07905694150420949f

typedef __attribute__((ext_vector_type(8))) short bf16x8;
typedef __attribute__((ext_vector_type(4))) float f32x4;
typedef __attribute__((ext_vector_type(4))) unsigned short u16x4;

__device__ __forceinline__ unsigned short f2bf(float f) {
    unsigned int u = __builtin_bit_cast(unsigned int, f);
    u = (u + 0x7FFFu + ((u >> 16) & 1u)) >> 16;
    return (unsigned short)u;
}

// ---------- elementwise f32 -> bf16 (wq) ----------
__global__ void k_cvt(const float* __restrict__ in, unsigned short* __restrict__ out, int n4) {
    int i = blockIdx.x * 256 + threadIdx.x;
    if (i >= n4) return;
    float4 v = ((const float4*)in)[i];
    u16x4 o = { f2bf(v.x), f2bf(v.y), f2bf(v.z), f2bf(v.w) };
    ((u16x4*)out)[i] = o;
}

// ---------- transpose+cvt: in f32 [R][C] -> out bf16 [C][R] ----------
__global__ void k_tcvt(const float* __restrict__ in, unsigned short* __restrict__ out,
                       int R, int C) {
    __shared__ float tile[32][33];
    int c0 = blockIdx.x * 32, r0 = blockIdx.y * 32;
    int tx = threadIdx.x, ty = threadIdx.y;
    for (int i = ty; i < 32; i += 8)
        tile[i][tx] = in[(size_t)(r0 + i) * C + c0 + tx];
    __syncthreads();
    for (int i = ty; i < 32; i += 8)
        out[(size_t)(c0 + i) * R + r0 + tx] = f2bf(tile[tx][i]);
}

// ---------- K/V projections via MFMA: KV[j*16+b][16 k][1280 e] bf16 ----------
// j: 0=K_anat(wk) 1=V_anat(wv) 2=K_dis(wkd) 3=V_dis(wvd) 4=K_delta(wkd) 5=V_delta(wvd)
__global__ __launch_bounds__(256)
void k_projM(const float* __restrict__ enc,
             const unsigned short* __restrict__ wTk, const unsigned short* __restrict__ wTv,
             const unsigned short* __restrict__ wTkd, const unsigned short* __restrict__ wTvd,
             unsigned short* __restrict__ KV) {
    int bid = blockIdx.x;
    int j = bid / 80, rem = bid % 80, b = rem / 5, nt = rem % 5;
    int tid = threadIdx.x, w = tid >> 6, l = tid & 63, l15 = l & 15, l4 = l >> 4;
    int tok0 = (j < 2) ? 16 : ((j < 4) ? 0 : 32);
    const unsigned short* wT = (j == 0) ? wTk : (j == 1) ? wTv : (j == 2 || j == 4) ? wTkd : wTvd;
    const float* ap = enc + ((size_t)(b * 48 + tok0 + l15)) * DC_;
    f32x4 zero = {0.f, 0.f, 0.f, 0.f};
    f32x4 acc[4];
    #pragma unroll
    for (int t = 0; t < 4; t++) acc[t] = zero;
    for (int kk = 0; kk < 24; kk++) {
        const float4* hp = (const float4*)(ap + kk * 32 + l4 * 8);
        float4 x0 = hp[0], x1 = hp[1];
        bf16x8 af;
        af[0] = (short)f2bf(x0.x); af[1] = (short)f2bf(x0.y);
        af[2] = (short)f2bf(x0.z); af[3] = (short)f2bf(x0.w);
        af[4] = (short)f2bf(x1.x); af[5] = (short)f2bf(x1.y);
        af[6] = (short)f2bf(x1.z); af[7] = (short)f2bf(x1.w);
        #pragma unroll
        for (int t = 0; t < 4; t++) {
            int n0 = nt * 256 + w * 64 + t * 16;
            bf16x8 bf = *(const bf16x8*)(wT + (size_t)(n0 + l15) * DC_ + kk * 32 + l4 * 8);
            acc[t] = __builtin_amdgcn_mfma_f32_16x16x32_bf16(af, bf, acc[t], 0, 0, 0);
        }
    }
    #pragma unroll
    for (int t = 0; t < 4; t++) {
        int e = nt * 256 + w * 64 + t * 16 + l15;
        #pragma unroll
        for (int r = 0; r < 4; r++)
            KV[((size_t)(j * 16 + b) * 16 + l4 * 4 + r) * DM_ + e] = f2bf(acc[t][r]);
    }
}

// ---------- A build via MFMA: At[b][c][d] bf16 (scale folded) ----------
__global__ __launch_bounds__(256)
void k_abuildM(const unsigned short* __restrict__ KV, const unsigned short* __restrict__ wqbf,
               unsigned short* __restrict__ At) {
    int bid = blockIdx.x;
    int b = bid & 15, r_ = bid >> 4, x = r_ >> 3, h = r_ & 7;
    int tid = threadIdx.x, w = tid >> 6, l = tid & 63, l15 = l & 15, l4 = l >> 4;
    bf16x8 bfr[5];
    #pragma unroll
    for (int kk = 0; kk < 5; kk++)
        bfr[kk] = *(const bf16x8*)(KV + ((size_t)((2 * x) * 16 + b) * 16 + l15) * DM_ + h * 160 + kk * 32 + l4 * 8);
    f32x4 zero = {0.f, 0.f, 0.f, 0.f};
    for (int tt = 0; tt < 20; tt++) {
        int d0 = w * 320 + tt * 16;
        f32x4 acc = zero;
        #pragma unroll
        for (int kk = 0; kk < 5; kk++) {
            bf16x8 af = *(const bf16x8*)(wqbf + (size_t)(d0 + l15) * DM_ + h * 160 + kk * 32 + l4 * 8);
            acc = __builtin_amdgcn_mfma_f32_16x16x32_bf16(af, bfr[kk], acc, 0, 0, 0);
        }
        u16x4 pk;
        #pragma unroll
        for (int r = 0; r < 4; r++) pk[r] = f2bf(acc[r] * SCALE_);
        *(u16x4*)(At + ((size_t)b * NC_ + (x * 8 + h) * 16 + l15) * DM_ + d0 + l4 * 4) = pk;
    }
}

// ---------- U build via MFMA: Ut[b][e][c] bf16 (gates folded) ----------
__global__ __launch_bounds__(256)
void k_ubuildM(const unsigned short* __restrict__ KV, const unsigned short* __restrict__ woutT,
               unsigned short* __restrict__ Ut) {
    int bid = blockIdx.x;
    int b = bid & 15, r_ = bid >> 4, x = r_ >> 3, h = r_ & 7;
    float gate = (x == 2) ? 1.0f : 0.5f;
    int tid = threadIdx.x, w = tid >> 6, l = tid & 63, l15 = l & 15, l4 = l >> 4;
    bf16x8 bfr[5];
    #pragma unroll
    for (int kk = 0; kk < 5; kk++)
        bfr[kk] = *(const bf16x8*)(KV + ((size_t)((2 * x + 1) * 16 + b) * 16 + l15) * DM_ + h * 160 + kk * 32 + l4 * 8);
    f32x4 zero = {0.f, 0.f, 0.f, 0.f};
    for (int tt = 0; tt < 20; tt++) {
        int e0 = w * 320 + tt * 16;
        f32x4 acc = zero;
        #pragma unroll
        for (int kk = 0; kk < 5; kk++) {
            bf16x8 af = *(const bf16x8*)(woutT + (size_t)(e0 + l15) * DM_ + h * 160 + kk * 32 + l4 * 8);
            acc = __builtin_amdgcn_mfma_f32_16x16x32_bf16(af, bfr[kk], acc, 0, 0, 0);
        }
        int c = (x * 8 + h) * 16 + l15;
        #pragma unroll
        for (int r = 0; r < 4; r++)
            Ut[((size_t)b * DM_ + e0 + l4 * 4 + r) * NC_ + c] = f2bf(acc[r] * gate);
    }
}

// ---------- scores = hidden @ A^T, softmax per 16-group, P bf16 ----------
__global__ __launch_bounds__(256, 2)
void k_scores(const float* __restrict__ hid, const unsigned short* __restrict__ At,
              unsigned short* __restrict__ P) {
    __shared__ unsigned short pnl[NC_ * 32];   // [384 c][32 j], chunk-XOR swizzled
    int bid = blockIdx.x;
    int b = bid & 15, t = bid >> 4;            // same-b blocks land on same XCD (bid mod 8 const)
    int s0 = t * 64;
    int tid = threadIdx.x;
    int w = tid >> 6, l = tid & 63;
    int l15 = l & 15, l4 = l >> 4;
    int rdsw = (l4 ^ ((l15 >> 1) & 3)) * 8;    // swizzled chunk for reads
    f32x4 zero = {0.f, 0.f, 0.f, 0.f};
    f32x4 acc[24];
    #pragma unroll
    for (int g = 0; g < 24; g++) acc[g] = zero;
    const unsigned short* Ab = At + (size_t)b * NC_ * DM_;
    const float* hrow = hid + ((size_t)b * S_ + s0 + w * 16 + l15) * DM_;
    for (int kk = 0; kk < 40; kk++) {
        #pragma unroll
        for (int i = 0; i < 6; i++) {          // linear LDS writes, pre-swizzled global src
            int idx = tid + 256 * i;
            int c = idx >> 2, m = (idx & 3) ^ ((c >> 1) & 3);
            uint4 v = *(const uint4*)(Ab + (size_t)c * DM_ + kk * 32 + m * 8);
            *(uint4*)&pnl[idx * 8] = v;
        }
        __syncthreads();
        const float4* hp = (const float4*)(hrow + kk * 32 + l4 * 8);
        float4 x0 = hp[0], x1 = hp[1];
        bf16x8 af;
        af[0] = (short)f2bf(x0.x); af[1] = (short)f2bf(x0.y);
        af[2] = (short)f2bf(x0.z); af[3] = (short)f2bf(x0.w);
        af[4] = (short)f2bf(x1.x); af[5] = (short)f2bf(x1.y);
        af[6] = (short)f2bf(x1.z); af[7] = (short)f2bf(x1.w);
        #pragma unroll
        for (int g = 0; g < 24; g++) {
            bf16x8 bf = *(const bf16x8*)&pnl[(g * 16 + l15) * 32 + rdsw];
            acc[g] = __builtin_amdgcn_mfma_f32_16x16x32_bf16(af, bf, acc[g], 0, 0, 0);
        }
        __syncthreads();
    }
    unsigned short* Pb = P + ((size_t)b * S_ + s0 + w * 16) * NC_;
    #pragma unroll
    for (int g = 0; g < 24; g++) {
        #pragma unroll
        for (int r = 0; r < 4; r++) {
            float v = acc[g][r];               // SCALE folded into At
            float mx = v;
            mx = fmaxf(mx, __shfl_xor(mx, 1));
            mx = fmaxf(mx, __shfl_xor(mx, 2));
            mx = fmaxf(mx, __shfl_xor(mx, 4));
            mx = fmaxf(mx, __shfl_xor(mx, 8));
            float ex = __expf(v - mx);
            float sm = ex;
            sm += __shfl_xor(sm, 1);
            sm += __shfl_xor(sm, 2);
            sm += __shfl_xor(sm, 4);
            sm += __shfl_xor(sm, 8);
            float p = ex / sm;
            Pb[(size_t)(l4 * 4 + r) * NC_ + g * 16 + l15] = f2bf(p);
        }
    }
}

// ---------- out = P @ U + b_out + residual ----------
__global__ __launch_bounds__(256, 2)
void k_out(const unsigned short* __restrict__ P, const unsigned short* __restrict__ Ut,
           const float* __restrict__ hid, const float* __restrict__ bo,
           float* __restrict__ out) {
    __shared__ unsigned short pnl[256 * 32];   // [256 e][32 c-chunk], chunk-XOR swizzled
    int bid = blockIdx.x;
    int b = bid & 15, t = bid >> 4;
    int s0 = t * 64;
    int tid = threadIdx.x;
    int w = tid >> 6, l = tid & 63;
    int l15 = l & 15, l4 = l >> 4;
    int rdsw = (l4 ^ ((l15 >> 1) & 3)) * 8;
    f32x4 zero = {0.f, 0.f, 0.f, 0.f};
    const unsigned short* Ub = Ut + (size_t)b * DM_ * NC_;
    const unsigned short* Prow = P + ((size_t)b * S_ + s0 + w * 16 + l15) * NC_;
    for (int ec = 0; ec < 5; ec++) {
        f32x4 acc[16];
        #pragma unroll
        for (int g = 0; g < 16; g++) acc[g] = zero;
        for (int kk = 0; kk < 12; kk++) {
            #pragma unroll
            for (int i = 0; i < 4; i++) {
                int idx = tid + 256 * i;
                int el = idx >> 2, m = (idx & 3) ^ ((el >> 1) & 3);
                uint4 v = *(const uint4*)(Ub + (size_t)(ec * 256 + el) * NC_ + kk * 32 + m * 8);
                *(uint4*)&pnl[idx * 8] = v;
            }
            __syncthreads();
            bf16x8 pa = *(const bf16x8*)(Prow + kk * 32 + l4 * 8);
            #pragma unroll
            for (int g = 0; g < 16; g++) {
                bf16x8 bv = *(const bf16x8*)&pnl[(g * 16 + l15) * 32 + rdsw];
                acc[g] = __builtin_amdgcn_mfma_f32_16x16x32_bf16(pa, bv, acc[g], 0, 0, 0);
            }
            __syncthreads();
        }
        #pragma unroll
        for (int g = 0; g < 16; g++) {
            #pragma unroll
            for (int r = 0; r < 4; r++) {
                int srow = s0 + w * 16 + l4 * 4 + r;
                int e = ec * 256 + g * 16 + l15;
                size_t off = ((size_t)b * S_ + srow) * DM_ + e;
                out[off] = acc[g][r] + bo[e] + hid[off];
            }
        }
    }
}

extern "C" void kernel_launch(void* const* d_in, const int* in_sizes, int n_in,
                              void* d_out, int out_size, void* d_ws, size_t ws_size,
                              hipStream_t stream) {
    const float* hid  = (const float*)d_in[0];
    const float* enc  = (const float*)d_in[1];
    const float* wq   = (const float*)d_in[2];
    const float* wk   = (const float*)d_in[3];
    const float* wv   = (const float*)d_in[4];
    const float* wkd  = (const float*)d_in[5];
    const float* wvd  = (const float*)d_in[6];
    const float* wout = (const float*)d_in[7];
    const float* bo   = (const float*)d_in[8];
    float* out = (float*)d_out;

    char* ws = (char*)d_ws;
    unsigned short* wq_bf  = (unsigned short*)(ws);               //  3,276,800 B
    unsigned short* woutT  = (unsigned short*)(ws +  3276800);    //  3,276,800 B
    unsigned short* wTk    = (unsigned short*)(ws +  6553600);    //  1,966,080 B
    unsigned short* wTv    = (unsigned short*)(ws +  8519680);    //  1,966,080 B
    unsigned short* wTkd   = (unsigned short*)(ws + 10485760);    //  1,966,080 B
    unsigned short* wTvd   = (unsigned short*)(ws + 12451840);    //  1,966,080 B
    unsigned short* KV     = (unsigned short*)(ws + 14417920);    //  3,932,160 B
    unsigned short* AtUt   = (unsigned short*)(ws + 18350080);    // 15,728,640 B (At, then Ut)
    unsigned short* Pbuf   = (unsigned short*)(ws + 34078720);    // 50,331,648 B (total 84.4 MB)

    k_cvt<<<1600, 256, 0, stream>>>(wq, wq_bf, 409600);
    k_tcvt<<<dim3(40, 24), dim3(32, 8), 0, stream>>>(wk,  wTk,  DC_, DM_);
    k_tcvt<<<dim3(40, 24), dim3(32, 8), 0, stream>>>(wv,  wTv,  DC_, DM_);
    k_tcvt<<<dim3(40, 24), dim3(32, 8), 0, stream>>>(wkd, wTkd, DC_, DM_);
    k_tcvt<<<dim3(40, 24), dim3(32, 8), 0, stream>>>(wvd, wTvd, DC_, DM_);
    k_tcvt<<<dim3(40, 40), dim3(32, 8), 0, stream>>>(wout, woutT, DM_, DM_);
    k_projM<<<480, 256, 0, stream>>>(enc, wTk, wTv, wTkd, wTvd, KV);
    k_abuildM<<<384, 256, 0, stream>>>(KV, wq_bf, AtUt);
    k_scores<<<1024, 256, 0, stream>>>(hid, AtUt, Pbuf);
    k_ubuildM<<<384, 256, 0, stream>>>(KV, woutT, AtUt);   // reuses At space after k_scores
    k_out<<<1024, 256, 0, stream>>>(Pbuf, AtUt, hid, bo, out);
}

// Round 3
// 583.780 us; speedup vs baseline: 1.7727x; 1.0778x over previous
//
#include <hip/hip_runtime.h>
#include <hip/hip_bf16.h>

#define B_ 16
#define S_ 4096
#define DM_ 1280
#define DC_ 768
#define NC_ 384
#define SCALE_ 0.07905694150420949f

typedef __attribute__((ext_vector_type(8))) short bf16x8;
typedef __attribute__((ext_vector_type(4))) float f32x4;
typedef __attribute__((ext_vector_type(4))) unsigned short u16x4;

__device__ __forceinline__ unsigned short f2bf(float f) {
    unsigned int u = __builtin_bit_cast(unsigned int, f);
    u = (u + 0x7FFFu + ((u >> 16) & 1u)) >> 16;
    return (unsigned short)u;
}

__device__ __forceinline__ bf16x8 pack8(float4 x0, float4 x1) {
    bf16x8 a;
    a[0] = (short)f2bf(x0.x); a[1] = (short)f2bf(x0.y);
    a[2] = (short)f2bf(x0.z); a[3] = (short)f2bf(x0.w);
    a[4] = (short)f2bf(x1.x); a[5] = (short)f2bf(x1.y);
    a[6] = (short)f2bf(x1.z); a[7] = (short)f2bf(x1.w);
    return a;
}

// ---------- elementwise f32 -> bf16 (wq) ----------
__global__ void k_cvt(const float* __restrict__ in, unsigned short* __restrict__ out, int n4) {
    int i = blockIdx.x * 256 + threadIdx.x;
    if (i >= n4) return;
    float4 v = ((const float4*)in)[i];
    u16x4 o = { f2bf(v.x), f2bf(v.y), f2bf(v.z), f2bf(v.w) };
    ((u16x4*)out)[i] = o;
}

// ---------- transpose+cvt: in f32 [R][C] -> out bf16 [C][R] ----------
__global__ void k_tcvt(const float* __restrict__ in, unsigned short* __restrict__ out,
                       int R, int C) {
    __shared__ float tile[32][33];
    int c0 = blockIdx.x * 32, r0 = blockIdx.y * 32;
    int tx = threadIdx.x, ty = threadIdx.y;
    for (int i = ty; i < 32; i += 8)
        tile[i][tx] = in[(size_t)(r0 + i) * C + c0 + tx];
    __syncthreads();
    for (int i = ty; i < 32; i += 8)
        out[(size_t)(c0 + i) * R + r0 + tx] = f2bf(tile[tx][i]);
}

// ---------- K/V projections via MFMA ----------
__global__ __launch_bounds__(256)
void k_projM(const float* __restrict__ enc,
             const unsigned short* __restrict__ wTk, const unsigned short* __restrict__ wTv,
             const unsigned short* __restrict__ wTkd, const unsigned short* __restrict__ wTvd,
             unsigned short* __restrict__ KV) {
    int bid = blockIdx.x;
    int j = bid / 80, rem = bid % 80, b = rem / 5, nt = rem % 5;
    int tid = threadIdx.x, w = tid >> 6, l = tid & 63, l15 = l & 15, l4 = l >> 4;
    int tok0 = (j < 2) ? 16 : ((j < 4) ? 0 : 32);
    const unsigned short* wT = (j == 0) ? wTk : (j == 1) ? wTv : (j == 2 || j == 4) ? wTkd : wTvd;
    const float* ap = enc + ((size_t)(b * 48 + tok0 + l15)) * DC_;
    f32x4 zero = {0.f, 0.f, 0.f, 0.f};
    f32x4 acc[4];
    #pragma unroll
    for (int t = 0; t < 4; t++) acc[t] = zero;
    for (int kk = 0; kk < 24; kk++) {
        const float4* hp = (const float4*)(ap + kk * 32 + l4 * 8);
        bf16x8 af = pack8(hp[0], hp[1]);
        #pragma unroll
        for (int t = 0; t < 4; t++) {
            int n0 = nt * 256 + w * 64 + t * 16;
            bf16x8 bf = *(const bf16x8*)(wT + (size_t)(n0 + l15) * DC_ + kk * 32 + l4 * 8);
            acc[t] = __builtin_amdgcn_mfma_f32_16x16x32_bf16(af, bf, acc[t], 0, 0, 0);
        }
    }
    #pragma unroll
    for (int t = 0; t < 4; t++) {
        int e = nt * 256 + w * 64 + t * 16 + l15;
        #pragma unroll
        for (int r = 0; r < 4; r++)
            KV[((size_t)(j * 16 + b) * 16 + l4 * 4 + r) * DM_ + e] = f2bf(acc[t][r]);
    }
}

// ---------- A build via MFMA: At[b][c][d] bf16 (scale folded) ----------
__global__ __launch_bounds__(256)
void k_abuildM(const unsigned short* __restrict__ KV, const unsigned short* __restrict__ wqbf,
               unsigned short* __restrict__ At) {
    int bid = blockIdx.x;
    int b = bid & 15, r_ = bid >> 4, x = r_ >> 3, h = r_ & 7;
    int tid = threadIdx.x, w = tid >> 6, l = tid & 63, l15 = l & 15, l4 = l >> 4;
    bf16x8 bfr[5];
    #pragma unroll
    for (int kk = 0; kk < 5; kk++)
        bfr[kk] = *(const bf16x8*)(KV + ((size_t)((2 * x) * 16 + b) * 16 + l15) * DM_ + h * 160 + kk * 32 + l4 * 8);
    f32x4 zero = {0.f, 0.f, 0.f, 0.f};
    for (int tt = 0; tt < 20; tt++) {
        int d0 = w * 320 + tt * 16;
        f32x4 acc = zero;
        #pragma unroll
        for (int kk = 0; kk < 5; kk++) {
            bf16x8 af = *(const bf16x8*)(wqbf + (size_t)(d0 + l15) * DM_ + h * 160 + kk * 32 + l4 * 8);
            acc = __builtin_amdgcn_mfma_f32_16x16x32_bf16(af, bfr[kk], acc, 0, 0, 0);
        }
        u16x4 pk;
        #pragma unroll
        for (int r = 0; r < 4; r++) pk[r] = f2bf(acc[r] * SCALE_);
        *(u16x4*)(At + ((size_t)b * NC_ + (x * 8 + h) * 16 + l15) * DM_ + d0 + l4 * 4) = pk;
    }
}

// ---------- U build via MFMA: Ut[b][e][c] bf16 (gates folded) ----------
__global__ __launch_bounds__(256)
void k_ubuildM(const unsigned short* __restrict__ KV, const unsigned short* __restrict__ woutT,
               unsigned short* __restrict__ Ut) {
    int bid = blockIdx.x;
    int b = bid & 15, r_ = bid >> 4, x = r_ >> 3, h = r_ & 7;
    float gate = (x == 2) ? 1.0f : 0.5f;
    int tid = threadIdx.x, w = tid >> 6, l = tid & 63, l15 = l & 15, l4 = l >> 4;
    bf16x8 bfr[5];
    #pragma unroll
    for (int kk = 0; kk < 5; kk++)
        bfr[kk] = *(const bf16x8*)(KV + ((size_t)((2 * x + 1) * 16 + b) * 16 + l15) * DM_ + h * 160 + kk * 32 + l4 * 8);
    f32x4 zero = {0.f, 0.f, 0.f, 0.f};
    for (int tt = 0; tt < 20; tt++) {
        int e0 = w * 320 + tt * 16;
        f32x4 acc = zero;
        #pragma unroll
        for (int kk = 0; kk < 5; kk++) {
            bf16x8 af = *(const bf16x8*)(woutT + (size_t)(e0 + l15) * DM_ + h * 160 + kk * 32 + l4 * 8);
            acc = __builtin_amdgcn_mfma_f32_16x16x32_bf16(af, bfr[kk], acc, 0, 0, 0);
        }
        int c = (x * 8 + h) * 16 + l15;
        #pragma unroll
        for (int r = 0; r < 4; r++)
            Ut[((size_t)b * DM_ + e0 + l4 * 4 + r) * NC_ + c] = f2bf(acc[r] * gate);
    }
}

// ---------- scores = hidden @ A^T (swapped), softmax, P bf16 ----------
__global__ __launch_bounds__(256, 3)
void k_scores(const float* __restrict__ hid, const unsigned short* __restrict__ At,
              unsigned short* __restrict__ P) {
    __shared__ unsigned short pnl[2][NC_ * 32];   // dbuf, chunk-XOR swizzled
    int bid = blockIdx.x;
    int b = bid & 15, t = bid >> 4;
    int s0 = t * 64;
    int tid = threadIdx.x;
    int w = tid >> 6, l = tid & 63;
    int l15 = l & 15, l4 = l >> 4;
    int rdsw = (l4 ^ ((l15 >> 1) & 3)) * 8;
    f32x4 zero = {0.f, 0.f, 0.f, 0.f};
    f32x4 acc[24];
    #pragma unroll
    for (int g = 0; g < 24; g++) acc[g] = zero;
    const unsigned short* Ab = At + (size_t)b * NC_ * DM_;
    const float* hrow = hid + ((size_t)b * S_ + s0 + w * 16 + l15) * DM_;

    uint4 sA[6]; float4 hA0, hA1;
    #pragma unroll
    for (int i = 0; i < 6; i++) {
        int idx = tid + 256 * i;
        int c = idx >> 2, m = (idx & 3) ^ ((c >> 1) & 3);
        sA[i] = *(const uint4*)(Ab + (size_t)c * DM_ + m * 8);
    }
    hA0 = *(const float4*)(hrow + l4 * 8);
    hA1 = *(const float4*)(hrow + l4 * 8 + 4);
    #pragma unroll
    for (int i = 0; i < 6; i++) *(uint4*)&pnl[0][(tid + 256 * i) * 8] = sA[i];
    __syncthreads();

    for (int kk = 0; kk < 40; kk++) {
        int cur = kk & 1;
        uint4 sN[6]; float4 hN0, hN1;
        if (kk < 39) {
            #pragma unroll
            for (int i = 0; i < 6; i++) {
                int idx = tid + 256 * i;
                int c = idx >> 2, m = (idx & 3) ^ ((c >> 1) & 3);
                sN[i] = *(const uint4*)(Ab + (size_t)c * DM_ + (kk + 1) * 32 + m * 8);
            }
            hN0 = *(const float4*)(hrow + (kk + 1) * 32 + l4 * 8);
            hN1 = *(const float4*)(hrow + (kk + 1) * 32 + l4 * 8 + 4);
        }
        bf16x8 af = pack8(hA0, hA1);
        #pragma unroll
        for (int g = 0; g < 24; g++) {
            bf16x8 bf = *(const bf16x8*)&pnl[cur][(g * 16 + l15) * 32 + rdsw];
            acc[g] = __builtin_amdgcn_mfma_f32_16x16x32_bf16(bf, af, acc[g], 0, 0, 0);
        }
        if (kk < 39) {
            #pragma unroll
            for (int i = 0; i < 6; i++) *(uint4*)&pnl[cur ^ 1][(tid + 256 * i) * 8] = sN[i];
        }
        __syncthreads();
        hA0 = hN0; hA1 = hN1;
    }

    // acc[g][r]: c = g*16 + l4*4 + r, s = s0 + w*16 + l15  -> softmax over c-group g
    unsigned short* Pb = P + ((size_t)b * S_ + s0 + w * 16 + l15) * NC_;
    #pragma unroll
    for (int g = 0; g < 24; g++) {
        float v0 = acc[g][0], v1 = acc[g][1], v2 = acc[g][2], v3 = acc[g][3];
        float mx = fmaxf(fmaxf(v0, v1), fmaxf(v2, v3));
        mx = fmaxf(mx, __shfl_xor(mx, 16));
        mx = fmaxf(mx, __shfl_xor(mx, 32));
        float e0 = __expf(v0 - mx), e1 = __expf(v1 - mx), e2 = __expf(v2 - mx), e3 = __expf(v3 - mx);
        float sm = e0 + e1 + e2 + e3;
        sm += __shfl_xor(sm, 16);
        sm += __shfl_xor(sm, 32);
        float rs = 1.0f / sm;
        u16x4 pk = { f2bf(e0 * rs), f2bf(e1 * rs), f2bf(e2 * rs), f2bf(e3 * rs) };
        *(u16x4*)(Pb + g * 16 + l4 * 4) = pk;
    }
}

// ---------- out = P @ U + b_out + residual (swapped -> float4 epilogue) ----------
__global__ __launch_bounds__(256, 4)
void k_out(const unsigned short* __restrict__ P, const unsigned short* __restrict__ Ut,
           const float* __restrict__ hid, const float* __restrict__ bo,
           float* __restrict__ out) {
    __shared__ unsigned short pnl[2][256 * 32];   // dbuf, chunk-XOR swizzled
    int bid = blockIdx.x;
    int b = bid & 15, t = bid >> 4;
    int s0 = t * 64;
    int tid = threadIdx.x;
    int w = tid >> 6, l = tid & 63;
    int l15 = l & 15, l4 = l >> 4;
    int rdsw = (l4 ^ ((l15 >> 1) & 3)) * 8;
    f32x4 zero = {0.f, 0.f, 0.f, 0.f};
    const unsigned short* Ub = Ut + (size_t)b * DM_ * NC_;
    const unsigned short* Prow = P + ((size_t)b * S_ + s0 + w * 16 + l15) * NC_;
    int srow = s0 + w * 16 + l15;

    for (int ec = 0; ec < 5; ec++) {
        f32x4 acc[16];
        #pragma unroll
        for (int g = 0; g < 16; g++) acc[g] = zero;

        uint4 sU[4];
        #pragma unroll
        for (int i = 0; i < 4; i++) {
            int idx = tid + 256 * i;
            int el = idx >> 2, m = (idx & 3) ^ ((el >> 1) & 3);
            sU[i] = *(const uint4*)(Ub + (size_t)(ec * 256 + el) * NC_ + m * 8);
        }
        bf16x8 pa = *(const bf16x8*)(Prow + l4 * 8);
        #pragma unroll
        for (int i = 0; i < 4; i++) *(uint4*)&pnl[0][(tid + 256 * i) * 8] = sU[i];
        __syncthreads();

        for (int kk = 0; kk < 12; kk++) {
            int cur = kk & 1;
            uint4 sN[4]; bf16x8 paN;
            if (kk < 11) {
                #pragma unroll
                for (int i = 0; i < 4; i++) {
                    int idx = tid + 256 * i;
                    int el = idx >> 2, m = (idx & 3) ^ ((el >> 1) & 3);
                    sN[i] = *(const uint4*)(Ub + (size_t)(ec * 256 + el) * NC_ + (kk + 1) * 32 + m * 8);
                }
                paN = *(const bf16x8*)(Prow + (kk + 1) * 32 + l4 * 8);
            }
            #pragma unroll
            for (int g = 0; g < 16; g++) {
                bf16x8 bv = *(const bf16x8*)&pnl[cur][(g * 16 + l15) * 32 + rdsw];
                acc[g] = __builtin_amdgcn_mfma_f32_16x16x32_bf16(bv, pa, acc[g], 0, 0, 0);
            }
            if (kk < 11) {
                #pragma unroll
                for (int i = 0; i < 4; i++) *(uint4*)&pnl[cur ^ 1][(tid + 256 * i) * 8] = sN[i];
            }
            __syncthreads();
            pa = paN;
        }

        // acc[g][r]: e = ec*256 + g*16 + l4*4 + r (consecutive in r), s = srow
        #pragma unroll
        for (int g = 0; g < 16; g++) {
            int e0 = ec * 256 + g * 16 + l4 * 4;
            size_t off = ((size_t)b * S_ + srow) * DM_ + e0;
            float4 h4 = *(const float4*)(hid + off);
            float4 b4 = *(const float4*)(bo + e0);
            float4 o4;
            o4.x = acc[g][0] + b4.x + h4.x;
            o4.y = acc[g][1] + b4.y + h4.y;
            o4.z = acc[g][2] + b4.z + h4.z;
            o4.w = acc[g][3] + b4.w + h4.w;
            *(float4*)(out + off) = o4;
        }
    }
}

extern "C" void kernel_launch(void* const* d_in, const int* in_sizes, int n_in,
                              void* d_out, int out_size, void* d_ws, size_t ws_size,
                              hipStream_t stream) {
    const float* hid  = (const float*)d_in[0];
    const float* enc  = (const float*)d_in[1];
    const float* wq   = (const float*)d_in[2];
    const float* wk   = (const float*)d_in[3];
    const float* wv   = (const float*)d_in[4];
    const float* wkd  = (const float*)d_in[5];
    const float* wvd  = (const float*)d_in[6];
    const float* wout = (const float*)d_in[7];
    const float* bo   = (const float*)d_in[8];
    float* out = (float*)d_out;

    char* ws = (char*)d_ws;
    unsigned short* wq_bf  = (unsigned short*)(ws);               //  3,276,800 B
    unsigned short* woutT  = (unsigned short*)(ws +  3276800);    //  3,276,800 B
    unsigned short* wTk    = (unsigned short*)(ws +  6553600);    //  1,966,080 B
    unsigned short* wTv    = (unsigned short*)(ws +  8519680);    //  1,966,080 B
    unsigned short* wTkd   = (unsigned short*)(ws + 10485760);    //  1,966,080 B
    unsigned short* wTvd   = (unsigned short*)(ws + 12451840);    //  1,966,080 B
    unsigned short* KV     = (unsigned short*)(ws + 14417920);    //  3,932,160 B
    unsigned short* AtUt   = (unsigned short*)(ws + 18350080);    // 15,728,640 B (At, then Ut)
    unsigned short* Pbuf   = (unsigned short*)(ws + 34078720);    // 50,331,648 B

    k_cvt<<<1600, 256, 0, stream>>>(wq, wq_bf, 409600);
    k_tcvt<<<dim3(40, 24), dim3(32, 8), 0, stream>>>(wk,  wTk,  DC_, DM_);
    k_tcvt<<<dim3(40, 24), dim3(32, 8), 0, stream>>>(wv,  wTv,  DC_, DM_);
    k_tcvt<<<dim3(40, 24), dim3(32, 8), 0, stream>>>(wkd, wTkd, DC_, DM_);
    k_tcvt<<<dim3(40, 24), dim3(32, 8), 0, stream>>>(wvd, wTvd, DC_, DM_);
    k_tcvt<<<dim3(40, 40), dim3(32, 8), 0, stream>>>(wout, woutT, DM_, DM_);
    k_projM<<<480, 256, 0, stream>>>(enc, wTk, wTv, wTkd, wTvd, KV);
    k_abuildM<<<384, 256, 0, stream>>>(KV, wq_bf, AtUt);
    k_scores<<<1024, 256, 0, stream>>>(hid, AtUt, Pbuf);
    k_ubuildM<<<384, 256, 0, stream>>>(KV, woutT, AtUt);   // reuses At space after k_scores
    k_out<<<1024, 256, 0, stream>>>(Pbuf, AtUt, hid, bo, out);
}

// Round 4
// 579.156 us; speedup vs baseline: 1.7868x; 1.0080x over previous
//
#include <hip/hip_runtime.h>
#include <hip/hip_bf16.h>

#define B_ 16
#define S_ 4096
#define DM_ 1280
#define DC_ 768
#define NC_ 384
#define SCALE_ 0.07905694150420949f

typedef __attribute__((ext_vector_type(8))) short bf16x8;
typedef __attribute__((ext_vector_type(4))) float f32x4;
typedef __attribute__((ext_vector_type(4))) unsigned short u16x4;

__device__ __forceinline__ unsigned short f2bf(float f) {
    unsigned int u = __builtin_bit_cast(unsigned int, f);
    u = (u + 0x7FFFu + ((u >> 16) & 1u)) >> 16;
    return (unsigned short)u;
}

__device__ __forceinline__ bf16x8 pack8(float4 x0, float4 x1) {
    bf16x8 a;
    a[0] = (short)f2bf(x0.x); a[1] = (short)f2bf(x0.y);
    a[2] = (short)f2bf(x0.z); a[3] = (short)f2bf(x0.w);
    a[4] = (short)f2bf(x1.x); a[5] = (short)f2bf(x1.y);
    a[6] = (short)f2bf(x1.z); a[7] = (short)f2bf(x1.w);
    return a;
}

// ---------- elementwise f32 -> bf16 (wq) ----------
__global__ void k_cvt(const float* __restrict__ in, unsigned short* __restrict__ out, int n4) {
    int i = blockIdx.x * 256 + threadIdx.x;
    if (i >= n4) return;
    float4 v = ((const float4*)in)[i];
    u16x4 o = { f2bf(v.x), f2bf(v.y), f2bf(v.z), f2bf(v.w) };
    ((u16x4*)out)[i] = o;
}

// ---------- transpose+cvt: in f32 [R][C] -> out bf16 [C][R] ----------
__global__ void k_tcvt(const float* __restrict__ in, unsigned short* __restrict__ out,
                       int R, int C) {
    __shared__ float tile[32][33];
    int c0 = blockIdx.x * 32, r0 = blockIdx.y * 32;
    int tx = threadIdx.x, ty = threadIdx.y;
    for (int i = ty; i < 32; i += 8)
        tile[i][tx] = in[(size_t)(r0 + i) * C + c0 + tx];
    __syncthreads();
    for (int i = ty; i < 32; i += 8)
        out[(size_t)(c0 + i) * R + r0 + tx] = f2bf(tile[tx][i]);
}

// ---------- K/V projections via MFMA ----------
__global__ __launch_bounds__(256)
void k_projM(const float* __restrict__ enc,
             const unsigned short* __restrict__ wTk, const unsigned short* __restrict__ wTv,
             const unsigned short* __restrict__ wTkd, const unsigned short* __restrict__ wTvd,
             unsigned short* __restrict__ KV) {
    int bid = blockIdx.x;
    int j = bid / 80, rem = bid % 80, b = rem / 5, nt = rem % 5;
    int tid = threadIdx.x, w = tid >> 6, l = tid & 63, l15 = l & 15, l4 = l >> 4;
    int tok0 = (j < 2) ? 16 : ((j < 4) ? 0 : 32);
    const unsigned short* wT = (j == 0) ? wTk : (j == 1) ? wTv : (j == 2 || j == 4) ? wTkd : wTvd;
    const float* ap = enc + ((size_t)(b * 48 + tok0 + l15)) * DC_;
    f32x4 zero = {0.f, 0.f, 0.f, 0.f};
    f32x4 acc[4];
    #pragma unroll
    for (int t = 0; t < 4; t++) acc[t] = zero;
    for (int kk = 0; kk < 24; kk++) {
        const float4* hp = (const float4*)(ap + kk * 32 + l4 * 8);
        bf16x8 af = pack8(hp[0], hp[1]);
        #pragma unroll
        for (int t = 0; t < 4; t++) {
            int n0 = nt * 256 + w * 64 + t * 16;
            bf16x8 bf = *(const bf16x8*)(wT + (size_t)(n0 + l15) * DC_ + kk * 32 + l4 * 8);
            acc[t] = __builtin_amdgcn_mfma_f32_16x16x32_bf16(af, bf, acc[t], 0, 0, 0);
        }
    }
    #pragma unroll
    for (int t = 0; t < 4; t++) {
        int e = nt * 256 + w * 64 + t * 16 + l15;
        #pragma unroll
        for (int r = 0; r < 4; r++)
            KV[((size_t)(j * 16 + b) * 16 + l4 * 4 + r) * DM_ + e] = f2bf(acc[t][r]);
    }
}

// ---------- A build via MFMA: At[b][c][d] bf16 (scale folded) ----------
__global__ __launch_bounds__(256)
void k_abuildM(const unsigned short* __restrict__ KV, const unsigned short* __restrict__ wqbf,
               unsigned short* __restrict__ At) {
    int bid = blockIdx.x;
    int b = bid & 15, r_ = bid >> 4, x = r_ >> 3, h = r_ & 7;
    int tid = threadIdx.x, w = tid >> 6, l = tid & 63, l15 = l & 15, l4 = l >> 4;
    bf16x8 bfr[5];
    #pragma unroll
    for (int kk = 0; kk < 5; kk++)
        bfr[kk] = *(const bf16x8*)(KV + ((size_t)((2 * x) * 16 + b) * 16 + l15) * DM_ + h * 160 + kk * 32 + l4 * 8);
    f32x4 zero = {0.f, 0.f, 0.f, 0.f};
    for (int tt = 0; tt < 20; tt++) {
        int d0 = w * 320 + tt * 16;
        f32x4 acc = zero;
        #pragma unroll
        for (int kk = 0; kk < 5; kk++) {
            bf16x8 af = *(const bf16x8*)(wqbf + (size_t)(d0 + l15) * DM_ + h * 160 + kk * 32 + l4 * 8);
            acc = __builtin_amdgcn_mfma_f32_16x16x32_bf16(af, bfr[kk], acc, 0, 0, 0);
        }
        u16x4 pk;
        #pragma unroll
        for (int r = 0; r < 4; r++) pk[r] = f2bf(acc[r] * SCALE_);
        *(u16x4*)(At + ((size_t)b * NC_ + (x * 8 + h) * 16 + l15) * DM_ + d0 + l4 * 4) = pk;
    }
}

// ---------- U build via MFMA: Ut[b][e][c] bf16 (gates folded) ----------
__global__ __launch_bounds__(256)
void k_ubuildM(const unsigned short* __restrict__ KV, const unsigned short* __restrict__ woutT,
               unsigned short* __restrict__ Ut) {
    int bid = blockIdx.x;
    int b = bid & 15, r_ = bid >> 4, x = r_ >> 3, h = r_ & 7;
    float gate = (x == 2) ? 1.0f : 0.5f;
    int tid = threadIdx.x, w = tid >> 6, l = tid & 63, l15 = l & 15, l4 = l >> 4;
    bf16x8 bfr[5];
    #pragma unroll
    for (int kk = 0; kk < 5; kk++)
        bfr[kk] = *(const bf16x8*)(KV + ((size_t)((2 * x + 1) * 16 + b) * 16 + l15) * DM_ + h * 160 + kk * 32 + l4 * 8);
    f32x4 zero = {0.f, 0.f, 0.f, 0.f};
    for (int tt = 0; tt < 20; tt++) {
        int e0 = w * 320 + tt * 16;
        f32x4 acc = zero;
        #pragma unroll
        for (int kk = 0; kk < 5; kk++) {
            bf16x8 af = *(const bf16x8*)(woutT + (size_t)(e0 + l15) * DM_ + h * 160 + kk * 32 + l4 * 8);
            acc = __builtin_amdgcn_mfma_f32_16x16x32_bf16(af, bfr[kk], acc, 0, 0, 0);
        }
        int c = (x * 8 + h) * 16 + l15;
        #pragma unroll
        for (int r = 0; r < 4; r++)
            Ut[((size_t)b * DM_ + e0 + l4 * 4 + r) * NC_ + c] = f2bf(acc[r] * gate);
    }
}

// ---------- fused: scores -> softmax -> P(LDS) -> PV + bias + residual ----------
__global__ __launch_bounds__(256, 2)
void k_fused(const float* __restrict__ hid, const unsigned short* __restrict__ At,
             const unsigned short* __restrict__ Ut, const float* __restrict__ bo,
             float* __restrict__ out) {
    __shared__ char smem[81920];
    unsigned short* Apnl = (unsigned short*)smem;            // scores: 2 x [384][32] (48 KB)
    unsigned short* Ulds = (unsigned short*)(smem + 49152);  // PV: 2 x [256][32] (32 KB)
    // P lives at smem[0..49152) during PV: [64 s][384 c] bf16, byte ^= (s&7)<<4

    int bid = blockIdx.x;
    int b = bid & 15, t = bid >> 4;
    int s0 = t * 64;
    int tid = threadIdx.x;
    int w = tid >> 6, l = tid & 63;
    int l15 = l & 15, l4 = l >> 4;
    int rdsw = (l4 ^ ((l15 >> 1) & 3)) * 8;
    f32x4 zero = {0.f, 0.f, 0.f, 0.f};

    // ================= scores phase =================
    {
        f32x4 acc[24];
        #pragma unroll
        for (int g = 0; g < 24; g++) acc[g] = zero;
        const unsigned short* Ab = At + (size_t)b * NC_ * DM_;
        const float* hrow = hid + ((size_t)b * S_ + s0 + w * 16 + l15) * DM_;

        uint4 sA[6]; float4 hA0, hA1;
        #pragma unroll
        for (int i = 0; i < 6; i++) {
            int idx = tid + 256 * i;
            int c = idx >> 2, m = (idx & 3) ^ ((c >> 1) & 3);
            sA[i] = *(const uint4*)(Ab + (size_t)c * DM_ + m * 8);
        }
        hA0 = *(const float4*)(hrow + l4 * 8);
        hA1 = *(const float4*)(hrow + l4 * 8 + 4);
        #pragma unroll
        for (int i = 0; i < 6; i++) *(uint4*)&Apnl[(tid + 256 * i) * 8] = sA[i];
        __syncthreads();

        for (int kk = 0; kk < 40; kk++) {
            int cur = kk & 1;
            uint4 sN[6]; float4 hN0, hN1;
            if (kk < 39) {
                #pragma unroll
                for (int i = 0; i < 6; i++) {
                    int idx = tid + 256 * i;
                    int c = idx >> 2, m = (idx & 3) ^ ((c >> 1) & 3);
                    sN[i] = *(const uint4*)(Ab + (size_t)c * DM_ + (kk + 1) * 32 + m * 8);
                }
                hN0 = *(const float4*)(hrow + (kk + 1) * 32 + l4 * 8);
                hN1 = *(const float4*)(hrow + (kk + 1) * 32 + l4 * 8 + 4);
            }
            bf16x8 af = pack8(hA0, hA1);
            #pragma unroll
            for (int g = 0; g < 24; g++) {
                bf16x8 bf = *(const bf16x8*)&Apnl[cur * 12288 + (g * 16 + l15) * 32 + rdsw];
                acc[g] = __builtin_amdgcn_mfma_f32_16x16x32_bf16(bf, af, acc[g], 0, 0, 0);
            }
            if (kk < 39) {
                #pragma unroll
                for (int i = 0; i < 6; i++) *(uint4*)&Apnl[(cur ^ 1) * 12288 + (tid + 256 * i) * 8] = sN[i];
            }
            __syncthreads();
            hA0 = hN0; hA1 = hN1;
        }

        // softmax per c-group, write P to LDS (swizzled)
        int s_l = w * 16 + l15;
        int sbase = s_l * 768;     // bytes: 384 c * 2B
        int sswz = (s_l & 7) << 4;
        #pragma unroll
        for (int g = 0; g < 24; g++) {
            float v0 = acc[g][0], v1 = acc[g][1], v2 = acc[g][2], v3 = acc[g][3];
            float mx = fmaxf(fmaxf(v0, v1), fmaxf(v2, v3));
            mx = fmaxf(mx, __shfl_xor(mx, 16));
            mx = fmaxf(mx, __shfl_xor(mx, 32));
            float e0 = __expf(v0 - mx), e1 = __expf(v1 - mx), e2 = __expf(v2 - mx), e3 = __expf(v3 - mx);
            float sm = e0 + e1 + e2 + e3;
            sm += __shfl_xor(sm, 16);
            sm += __shfl_xor(sm, 32);
            float rs = 1.0f / sm;
            u16x4 pk = { f2bf(e0 * rs), f2bf(e1 * rs), f2bf(e2 * rs), f2bf(e3 * rs) };
            int byteoff = (sbase + g * 32 + l4 * 8) ^ sswz;
            *(u16x4*)(smem + byteoff) = pk;
        }
    }

    // stage U(ec=0, kk=0) into buf 0
    const unsigned short* Ub = Ut + (size_t)b * DM_ * NC_;
    #pragma unroll
    for (int i = 0; i < 4; i++) {
        int idx = tid + 256 * i;
        int el = idx >> 2, m = (idx & 3) ^ ((el >> 1) & 3);
        uint4 v = *(const uint4*)(Ub + (size_t)el * NC_ + m * 8);
        *(uint4*)&Ulds[idx * 8] = v;
    }
    __syncthreads();

    // ================= PV phase: wave = 64 e x 64 s =================
    int cur = 0;
    for (int ec = 0; ec < 5; ec++) {
        f32x4 acc[16];
        #pragma unroll
        for (int g = 0; g < 16; g++) acc[g] = zero;

        for (int kk = 0; kk < 12; kk++) {
            bool has_next = !(ec == 4 && kk == 11);
            int nec = (kk == 11) ? ec + 1 : ec;
            int nkk = (kk == 11) ? 0 : kk + 1;
            uint4 sN[4];
            if (has_next) {
                #pragma unroll
                for (int i = 0; i < 4; i++) {
                    int idx = tid + 256 * i;
                    int el = idx >> 2, m = (idx & 3) ^ ((el >> 1) & 3);
                    sN[i] = *(const uint4*)(Ub + (size_t)(nec * 256 + el) * NC_ + nkk * 32 + m * 8);
                }
            }
            bf16x8 bv[4], pv[4];
            #pragma unroll
            for (int mt = 0; mt < 4; mt++)
                bv[mt] = *(const bf16x8*)&Ulds[cur * 8192 + (w * 64 + mt * 16 + l15) * 32 + rdsw];
            #pragma unroll
            for (int sg = 0; sg < 4; sg++) {
                int s_l = sg * 16 + l15;
                int byteoff = (s_l * 768 + kk * 64 + l4 * 16) ^ ((s_l & 7) << 4);
                pv[sg] = *(const bf16x8*)(smem + byteoff);
            }
            #pragma unroll
            for (int sg = 0; sg < 4; sg++)
                #pragma unroll
                for (int mt = 0; mt < 4; mt++)
                    acc[sg * 4 + mt] = __builtin_amdgcn_mfma_f32_16x16x32_bf16(bv[mt], pv[sg], acc[sg * 4 + mt], 0, 0, 0);
            if (has_next) {
                #pragma unroll
                for (int i = 0; i < 4; i++) *(uint4*)&Ulds[(cur ^ 1) * 8192 + (tid + 256 * i) * 8] = sN[i];
            }
            __syncthreads();
            cur ^= 1;
        }

        // epilogue: e = ec*256 + w*64 + mt*16 + l4*4 + r, s = s0 + sg*16 + l15
        #pragma unroll
        for (int sg = 0; sg < 4; sg++) {
            int srow = s0 + sg * 16 + l15;
            #pragma unroll
            for (int mt = 0; mt < 4; mt++) {
                int e0 = ec * 256 + w * 64 + mt * 16 + l4 * 4;
                size_t off = ((size_t)b * S_ + srow) * DM_ + e0;
                float4 h4 = *(const float4*)(hid + off);
                float4 b4 = *(const float4*)(bo + e0);
                f32x4 a = acc[sg * 4 + mt];
                float4 o4;
                o4.x = a[0] + b4.x + h4.x;
                o4.y = a[1] + b4.y + h4.y;
                o4.z = a[2] + b4.z + h4.z;
                o4.w = a[3] + b4.w + h4.w;
                *(float4*)(out + off) = o4;
            }
        }
    }
}

extern "C" void kernel_launch(void* const* d_in, const int* in_sizes, int n_in,
                              void* d_out, int out_size, void* d_ws, size_t ws_size,
                              hipStream_t stream) {
    const float* hid  = (const float*)d_in[0];
    const float* enc  = (const float*)d_in[1];
    const float* wq   = (const float*)d_in[2];
    const float* wk   = (const float*)d_in[3];
    const float* wv   = (const float*)d_in[4];
    const float* wkd  = (const float*)d_in[5];
    const float* wvd  = (const float*)d_in[6];
    const float* wout = (const float*)d_in[7];
    const float* bo   = (const float*)d_in[8];
    float* out = (float*)d_out;

    char* ws = (char*)d_ws;
    unsigned short* wq_bf  = (unsigned short*)(ws);               //  3,276,800 B
    unsigned short* woutT  = (unsigned short*)(ws +  3276800);    //  3,276,800 B
    unsigned short* wTk    = (unsigned short*)(ws +  6553600);    //  1,966,080 B
    unsigned short* wTv    = (unsigned short*)(ws +  8519680);    //  1,966,080 B
    unsigned short* wTkd   = (unsigned short*)(ws + 10485760);    //  1,966,080 B
    unsigned short* wTvd   = (unsigned short*)(ws + 12451840);    //  1,966,080 B
    unsigned short* KV     = (unsigned short*)(ws + 14417920);    //  3,932,160 B
    unsigned short* At     = (unsigned short*)(ws + 18350080);    // 15,728,640 B
    unsigned short* Ut     = (unsigned short*)(ws + 34078720);    // 15,728,640 B (~49.8 MB total)

    k_cvt<<<1600, 256, 0, stream>>>(wq, wq_bf, 409600);
    k_tcvt<<<dim3(40, 24), dim3(32, 8), 0, stream>>>(wk,  wTk,  DC_, DM_);
    k_tcvt<<<dim3(40, 24), dim3(32, 8), 0, stream>>>(wv,  wTv,  DC_, DM_);
    k_tcvt<<<dim3(40, 24), dim3(32, 8), 0, stream>>>(wkd, wTkd, DC_, DM_);
    k_tcvt<<<dim3(40, 24), dim3(32, 8), 0, stream>>>(wvd, wTvd, DC_, DM_);
    k_tcvt<<<dim3(40, 40), dim3(32, 8), 0, stream>>>(wout, woutT, DM_, DM_);
    k_projM<<<480, 256, 0, stream>>>(enc, wTk, wTv, wTkd, wTvd, KV);
    k_abuildM<<<384, 256, 0, stream>>>(KV, wq_bf, At);
    k_ubuildM<<<384, 256, 0, stream>>>(KV, woutT, Ut);
    k_fused<<<1024, 256, 0, stream>>>(hid, At, Ut, bo, out);
}